// Round 5
// baseline (182.652 us; speedup 1.0000x reference)
//
#include <hip/hip_runtime.h>
#include <hip/hip_bf16.h>

// Problem constants
#define Bdim 2
#define Nseq 2048
#define Dmod 1024
#define Hn   16
#define HDim 64

#define XN  (Bdim * Nseq * Dmod)        // 4,194,304
#define WQN (3 * Dmod * Dmod)           // 3,145,728
#define WON (Dmod * Dmod)               // 1,048,576

typedef __attribute__((ext_vector_type(8))) __bf16 bf16x8;
typedef __attribute__((ext_vector_type(4))) __bf16 bf16x4;
typedef __attribute__((ext_vector_type(4))) float  floatx4;

__device__ __forceinline__ floatx4 mfma16(bf16x8 a, bf16x8 b, floatx4 c) {
    return __builtin_amdgcn_mfma_f32_16x16x32_bf16(a, b, c, 0, 0, 0);
}

// native v_exp_f32 computes 2^x
__device__ __forceinline__ float exp2v(float x) {
    return __builtin_amdgcn_exp2f(x);
}

// async global->LDS, 16 B per lane (GEMMs only; attn uses swizzled ds_write).
__device__ __forceinline__ void async_copy16(__bf16* l, const __bf16* g) {
    __builtin_amdgcn_global_load_lds(
        (const __attribute__((address_space(1))) void*)g,
        (__attribute__((address_space(3))) void*)l,
        16, 0, 0);
}

// ---------------------------------------------------------------------------
// Kernel 0: fp32 -> bf16 conversion. 8 elems/thread: 2x float4 load (32 B)
// + 1x bf16x8 store (16 B/lane = coalescing sweet spot).
// ---------------------------------------------------------------------------
__global__ __launch_bounds__(256) void convert_kernel(
    const float* __restrict__ x, const float* __restrict__ wq,
    const float* __restrict__ wo,
    __bf16* __restrict__ xb, __bf16* __restrict__ wqb, __bf16* __restrict__ wob)
{
    int i = (blockIdx.x * 256 + threadIdx.x) * 8;
    const float* src;
    __bf16* dst;
    int off;
    if (i < XN)            { src = x;  dst = xb;  off = i; }
    else if (i < XN + WQN) { src = wq; dst = wqb; off = i - XN; }
    else                   { src = wo; dst = wob; off = i - XN - WQN; }
    float4 v0 = *(const float4*)(src + off);
    float4 v1 = *(const float4*)(src + off + 4);
    bf16x8 o;
    o[0] = (__bf16)v0.x; o[1] = (__bf16)v0.y; o[2] = (__bf16)v0.z; o[3] = (__bf16)v0.w;
    o[4] = (__bf16)v1.x; o[5] = (__bf16)v1.y; o[6] = (__bf16)v1.z; o[7] = (__bf16)v1.w;
    *(bf16x8*)(dst + off) = o;
}

// ---------------------------------------------------------------------------
// Kernel 1: QKV projection — PROVEN R1 version restored verbatim (43.4us,
// m97-style 128x128, BK=32, single-buffer). R4's dbuf stage-ahead regressed
// to 69us: __syncthreads drains vmcnt(0) of the just-issued next-tile loads,
// so the pipeline had zero depth but paid 2x LDS.
// Q third pre-scaled by C = hd^-0.5 * log2(e) (attention runs in log2 domain).
// ---------------------------------------------------------------------------
__global__ __launch_bounds__(256) void qkv_kernel(
    const __bf16* __restrict__ x, const __bf16* __restrict__ Wq,
    const float* __restrict__ bq,
    __bf16* __restrict__ qb, __bf16* __restrict__ kb, __bf16* __restrict__ vt)
{
    __shared__ __align__(16) __bf16 ldsA[128 * 32];
    __shared__ __align__(16) __bf16 ldsB[128 * 32];

    const int tid  = threadIdx.x;
    const int lane = tid & 63, l16 = lane & 15, quad = lane >> 4;
    const int wiw  = tid >> 6;
    const int wm   = wiw & 1, wn = wiw >> 1;

    const int bm = blockIdx.x & 31;             // 32 m-tiles (M=4096)
    const int bn = blockIdx.x >> 5;             // 24 n-tiles (N=3072)
    const int m0 = bm * 128, n0 = bn * 128;

    const int srow = tid >> 2;                  // staging row 0..63
    const int scol = (tid & 3) * 8;             // staging col {0,8,16,24}

    floatx4 z = {0.f, 0.f, 0.f, 0.f};
    floatx4 acc[4][4];
    #pragma unroll
    for (int mt = 0; mt < 4; ++mt)
        #pragma unroll
        for (int nt = 0; nt < 4; ++nt) acc[mt][nt] = z;

    const __bf16* ga = x  + (size_t)m0 * Dmod;
    const __bf16* gb = Wq + (size_t)n0 * Dmod;

    for (int k0 = 0; k0 < Dmod; k0 += 32) {
        async_copy16(&ldsA[srow * 32 + scol],        ga + (size_t)srow * Dmod + k0 + scol);
        async_copy16(&ldsA[(64 + srow) * 32 + scol], ga + (size_t)(64 + srow) * Dmod + k0 + scol);
        async_copy16(&ldsB[srow * 32 + scol],        gb + (size_t)srow * Dmod + k0 + scol);
        async_copy16(&ldsB[(64 + srow) * 32 + scol], gb + (size_t)(64 + srow) * Dmod + k0 + scol);
        __syncthreads();

        bf16x8 af[4], bfr[4];
        #pragma unroll
        for (int mt = 0; mt < 4; ++mt)
            af[mt] = *(const bf16x8*)&ldsA[(wm * 64 + mt * 16 + l16) * 32 + quad * 8];
        #pragma unroll
        for (int nt = 0; nt < 4; ++nt)
            bfr[nt] = *(const bf16x8*)&ldsB[(wn * 64 + nt * 16 + l16) * 32 + quad * 8];
        #pragma unroll
        for (int mt = 0; mt < 4; ++mt)
            #pragma unroll
            for (int nt = 0; nt < 4; ++nt)
                acc[mt][nt] = mfma16(af[mt], bfr[nt], acc[mt][nt]);
        __syncthreads();
    }

    const int nb    = n0 + wn * 64;
    const int which = nb >> 10;
    const int h     = (nb & 1023) >> 6;
    const int mw    = m0 + wm * 64;
    const int bi    = mw >> 11;
    const int pos0  = mw & (Nseq - 1);

    const float qscale = 0.18033688f;           // 0.125 * log2(e)

    #pragma unroll
    for (int nt = 0; nt < 4; ++nt) {
        float bias = bq[nb + nt * 16 + l16];
        int hd = nt * 16 + l16;
        #pragma unroll
        for (int mt = 0; mt < 4; ++mt)
            #pragma unroll
            for (int i = 0; i < 4; ++i) {
                int pos = pos0 + mt * 16 + quad * 4 + i;
                float r = acc[mt][nt][i] + bias;
                if (which == 0)
                    qb[((bi * Hn + h) * Nseq + pos) * HDim + hd] = (__bf16)(r * qscale);
                else if (which == 1)
                    kb[((bi * Hn + h) * Nseq + pos) * HDim + hd] = (__bf16)r;
                else
                    vt[((bi * Hn + h) * HDim + hd) * Nseq + pos] = (__bf16)r;
            }
    }
}

// ---------------------------------------------------------------------------
// Kernel 2: causal flash attention — R5: 32 queries/wave (128 q/block).
// Same proven R1 staging/barrier skeleton (register prefetch -> swizzled
// ds_write -> sync -> QK -> softmax -> P via LDS -> PV -> sync), but each
// K/V tile now feeds 2 q-subtiles: MFMA per iter doubles while staging,
// barriers and K/V LDS reads stay constant, and total tile-iterations per
// head drop from 528 to 272 (34/CU, pair-balanced {15-k, k}).
// VGPR-heavy (~160) but grid = 512 = 2 blocks/CU -> occupancy grid-limited,
// so extra registers are free; launch_bounds (256,2).
// ---------------------------------------------------------------------------
__global__ __launch_bounds__(256, 2) void attn_kernel(
    const __bf16* __restrict__ qbuf, const __bf16* __restrict__ kbuf,
    const __bf16* __restrict__ vtbuf, __bf16* __restrict__ aout)
{
    __shared__ __align__(16) __bf16 ldsK[64 * 64];    // [key][d], swizzled
    __shared__ __align__(16) __bf16 ldsV[64 * 64];    // [d][key], swizzled
    __shared__ __align__(16) __bf16 ldsP[4][2 * 16 * 72]; // per wave: 2 subtiles

    const int tid  = threadIdx.x;
    const int wiw  = tid >> 6;
    const int lane = tid & 63, l16 = lane & 15, quad = lane >> 4;
    const int b    = blockIdx.x;
    const int bh   = b & 31;                    // head; 16 q-blocks per head
    // Balanced remap: CU hosts blocks {i, i+256} -> g pairs {k, k+8} ->
    // qblk {15-k, k} -> per-CU work = (2(15-k)+2)+(2k+2) = 34 tiles, all k.
    const int g  = b >> 5;                      // 0..15
    const int gk = g & 7;
    const int qblk = (g >> 3) == 0 ? 15 - gk : gk;

    const int q0w   = qblk * 128 + wiw * 32;    // wave's first query
    const int qloc0 = wiw * 32 + l16;           // block-local q row, subtile 0
    const int qloc1 = qloc0 + 16;               //                   subtile 1

    const __bf16* qs = qbuf  + bh * Nseq * HDim;
    const __bf16* ks = kbuf  + bh * Nseq * HDim;
    const __bf16* vs = vtbuf + bh * HDim * Nseq;

    // staging coords: thread handles rows sr, sr+32; 16B block sb
    const int sr  = tid >> 3;                   // 0..31
    const int sb  = tid & 7;                    // 0..7
    const int swr = (sb ^ (sr & 7)) * 8;        // swizzled block offset (elems)
    const int wk0 = sr * 64 + swr;              // (sr+32)&7 == sr&7
    const int wk1 = (sr + 32) * 64 + swr;

    // Q as B-operand: lane l16 = q row; two q-subtiles, two d-halves each.
    bf16x8 qf00 = *(const bf16x8*)(qs + (q0w + l16) * HDim + quad * 8);
    bf16x8 qf01 = *(const bf16x8*)(qs + (q0w + l16) * HDim + 32 + quad * 8);
    bf16x8 qf10 = *(const bf16x8*)(qs + (q0w + 16 + l16) * HDim + quad * 8);
    bf16x8 qf11 = *(const bf16x8*)(qs + (q0w + 16 + l16) * HDim + 32 + quad * 8);

    floatx4 z = {0.f, 0.f, 0.f, 0.f};
    floatx4 o[4][2];
    #pragma unroll
    for (int s = 0; s < 4; ++s) { o[s][0] = z; o[s][1] = z; }
    floatx4 lacc0 = z, lacc1 = z;               // ones-MFMA row-sums
    float m_i0 = -1e30f, m_i1 = -1e30f;

    bf16x8 ones;
    #pragma unroll
    for (int j = 0; j < 8; ++j) ones[j] = (__bf16)1.0f;

    const int nkt = 2 * qblk + 2;               // 64-key tiles
    __bf16* myp = ldsP[wiw];
    const int swz = l16 & 7;                    // read-side swizzle (row&7)

    // prefetch tile 0 into registers
    float4 rk0 = *(const float4*)(ks + (size_t)sr * HDim + sb * 8);
    float4 rk1 = *(const float4*)(ks + (size_t)(sr + 32) * HDim + sb * 8);
    float4 rv0 = *(const float4*)(vs + (size_t)sr * Nseq + sb * 8);
    float4 rv1 = *(const float4*)(vs + (size_t)(sr + 32) * Nseq + sb * 8);

    for (int kt = 0; kt < nkt; ++kt) {
        // issue next tile's global loads first (in flight during compute)
        float4 nk0 = {}, nk1 = {}, nv0 = {}, nv1 = {};
        if (kt + 1 < nkt) {
            const int k0n = (kt + 1) * 64;
            nk0 = *(const float4*)(ks + (size_t)(k0n + sr) * HDim + sb * 8);
            nk1 = *(const float4*)(ks + (size_t)(k0n + sr + 32) * HDim + sb * 8);
            nv0 = *(const float4*)(vs + (size_t)sr * Nseq + k0n + sb * 8);
            nv1 = *(const float4*)(vs + (size_t)(sr + 32) * Nseq + k0n + sb * 8);
        }

        // write current tile to LDS (swizzled)
        *(float4*)&ldsK[wk0] = rk0;
        *(float4*)&ldsK[wk1] = rk1;
        *(float4*)&ldsV[wk0] = rv0;
        *(float4*)&ldsV[wk1] = rv1;
        __syncthreads();

        // S^T: 4 key-subtiles x 2 q-subtiles. A=K (m=key), B=Q (n=q).
        // K fragments loaded once, reused for both q-subtiles.
        floatx4 st[4][2];
        __builtin_amdgcn_s_setprio(1);
        #pragma unroll
        for (int t = 0; t < 4; ++t) {
            const __bf16* kr = &ldsK[(t * 16 + l16) * 64];
            bf16x8 kf0 = *(const bf16x8*)(kr + ((quad ^ swz) * 8));
            bf16x8 kf1 = *(const bf16x8*)(kr + (((quad + 4) ^ swz) * 8));
            st[t][0] = mfma16(kf0, qf00, z);
            st[t][0] = mfma16(kf1, qf01, st[t][0]);
            st[t][1] = mfma16(kf0, qf10, z);
            st[t][1] = mfma16(kf1, qf11, st[t][1]);
        }
        __builtin_amdgcn_s_setprio(0);

        // scores (log2 domain, scale pre-folded into Q);
        // lane holds keys {16t+quad*4+i}. Mask only the last two tiles.
        const bool maskt = (kt >= nkt - 2);
        const int  koff  = kt * 64 - qblk * 128;     // 0 or 64 when maskt
        float a0[16], a1[16];
        #pragma unroll
        for (int t = 0; t < 4; ++t)
            #pragma unroll
            for (int i = 0; i < 4; ++i) {
                float v0 = st[t][0][i], v1 = st[t][1][i];
                if (maskt) {
                    int kidx = koff + t * 16 + quad * 4 + i;  // block-local key
                    v0 = (kidx <= qloc0) ? v0 : -1e30f;
                    v1 = (kidx <= qloc1) ? v1 : -1e30f;
                }
                a0[t * 4 + i] = v0;
                a1[t * 4 + i] = v1;
            }

        // row max per subtile: max3-shaped tree + 2 cross-quad shuffles
        float x0 = fmaxf(fmaxf(a0[0], a0[1]), a0[2]);
        float x1 = fmaxf(fmaxf(a0[3], a0[4]), a0[5]);
        float x2 = fmaxf(fmaxf(a0[6], a0[7]), a0[8]);
        float x3 = fmaxf(fmaxf(a0[9], a0[10]), a0[11]);
        float x4 = fmaxf(fmaxf(a0[12], a0[13]), a0[14]);
        float mx0 = fmaxf(fmaxf(fmaxf(x0, x1), x2), fmaxf(fmaxf(x3, x4), a0[15]));
        mx0 = fmaxf(mx0, __shfl_xor(mx0, 16));
        mx0 = fmaxf(mx0, __shfl_xor(mx0, 32));
        float y0 = fmaxf(fmaxf(a1[0], a1[1]), a1[2]);
        float y1 = fmaxf(fmaxf(a1[3], a1[4]), a1[5]);
        float y2 = fmaxf(fmaxf(a1[6], a1[7]), a1[8]);
        float y3 = fmaxf(fmaxf(a1[9], a1[10]), a1[11]);
        float y4 = fmaxf(fmaxf(a1[12], a1[13]), a1[14]);
        float mx1 = fmaxf(fmaxf(fmaxf(y0, y1), y2), fmaxf(fmaxf(y3, y4), a1[15]));
        mx1 = fmaxf(mx1, __shfl_xor(mx1, 16));
        mx1 = fmaxf(mx1, __shfl_xor(mx1, 32));

        // defer-max (THR=8 log2 units), combined vote for both subtiles
        if (__any((mx0 > m_i0 + 8.0f) || (mx1 > m_i1 + 8.0f))) {
            float mn0 = fmaxf(m_i0, mx0), mn1 = fmaxf(m_i1, mx1);
            float al0 = exp2v(m_i0 - mn0), al1 = exp2v(m_i1 - mn1);
            #pragma unroll
            for (int s = 0; s < 4; ++s)
                #pragma unroll
                for (int i = 0; i < 4; ++i) {
                    o[s][0][i] *= al0;
                    o[s][1][i] *= al1;
                }
            #pragma unroll
            for (int i = 0; i < 4; ++i) { lacc0[i] *= al0; lacc1[i] *= al1; }
            m_i0 = mn0; m_i1 = mn1;
        }

        float p0[16], p1[16];
        #pragma unroll
        for (int j = 0; j < 16; ++j) {
            p0[j] = exp2v(a0[j] - m_i0);
            p1[j] = exp2v(a1[j] - m_i1);
        }

        // P: C-layout -> LDS -> B-layout (per-wave region, 2 subtiles)
        #pragma unroll
        for (int t = 0; t < 4; ++t) {
            bf16x4 pk0, pk1;
            pk0.x = (__bf16)p0[t * 4 + 0]; pk0.y = (__bf16)p0[t * 4 + 1];
            pk0.z = (__bf16)p0[t * 4 + 2]; pk0.w = (__bf16)p0[t * 4 + 3];
            pk1.x = (__bf16)p1[t * 4 + 0]; pk1.y = (__bf16)p1[t * 4 + 1];
            pk1.z = (__bf16)p1[t * 4 + 2]; pk1.w = (__bf16)p1[t * 4 + 3];
            *(bf16x4*)(myp + l16 * 72 + t * 16 + quad * 4)        = pk0;
            *(bf16x4*)(myp + 1152 + l16 * 72 + t * 16 + quad * 4) = pk1;
        }
        asm volatile("s_waitcnt lgkmcnt(0)" ::: "memory");
        bf16x8 pf00 = *(const bf16x8*)(myp + l16 * 72 + quad * 8);
        bf16x8 pf01 = *(const bf16x8*)(myp + l16 * 72 + 32 + quad * 8);
        bf16x8 pf10 = *(const bf16x8*)(myp + 1152 + l16 * 72 + quad * 8);
        bf16x8 pf11 = *(const bf16x8*)(myp + 1152 + l16 * 72 + 32 + quad * 8);

        __builtin_amdgcn_s_setprio(1);
        // row-sums via ones-MFMA (bf16 P, consistent with the P used for O)
        lacc0 = mfma16(ones, pf00, lacc0);
        lacc0 = mfma16(ones, pf01, lacc0);
        lacc1 = mfma16(ones, pf10, lacc1);
        lacc1 = mfma16(ones, pf11, lacc1);

        // O^T += V^T P^T : A=V^T (m=d, k=key) from LDS (swizzled);
        // V fragments loaded once, reused for both q-subtiles.
        #pragma unroll
        for (int s = 0; s < 4; ++s) {
            const __bf16* vr = &ldsV[(s * 16 + l16) * 64];
            bf16x8 vf0 = *(const bf16x8*)(vr + ((quad ^ swz) * 8));
            bf16x8 vf1 = *(const bf16x8*)(vr + (((quad + 4) ^ swz) * 8));
            o[s][0] = mfma16(vf0, pf00, o[s][0]);
            o[s][0] = mfma16(vf1, pf01, o[s][0]);
            o[s][1] = mfma16(vf0, pf10, o[s][1]);
            o[s][1] = mfma16(vf1, pf11, o[s][1]);
        }
        __builtin_amdgcn_s_setprio(0);
        __syncthreads();                        // all waves done with K/V tile

        rk0 = nk0; rk1 = nk1; rv0 = nv0; rv1 = nv1;
    }

    // Epilogue: O^T tile s: row = d = s*16+quad*4, col = q = q0w + u*16 + l16
    const float inv0 = 1.0f / lacc0[0];
    const float inv1 = 1.0f / lacc1[0];
    const int bi = bh >> 4, h = bh & 15;
    #pragma unroll
    for (int s = 0; s < 4; ++s) {
        bf16x4 ov0, ov1;
        ov0.x = (__bf16)(o[s][0][0] * inv0); ov0.y = (__bf16)(o[s][0][1] * inv0);
        ov0.z = (__bf16)(o[s][0][2] * inv0); ov0.w = (__bf16)(o[s][0][3] * inv0);
        ov1.x = (__bf16)(o[s][1][0] * inv1); ov1.y = (__bf16)(o[s][1][1] * inv1);
        ov1.z = (__bf16)(o[s][1][2] * inv1); ov1.w = (__bf16)(o[s][1][3] * inv1);
        *(bf16x4*)(aout + ((size_t)(bi * Nseq + q0w + l16)) * Dmod
                   + h * 64 + s * 16 + quad * 4) = ov0;
        *(bf16x4*)(aout + ((size_t)(bi * Nseq + q0w + 16 + l16)) * Dmod
                   + h * 64 + s * 16 + quad * 4) = ov1;
    }
}

// ---------------------------------------------------------------------------
// Kernel 3: output projection — PROVEN R1 version restored verbatim
// (BM=64 x BN=128, BK=32, single-buffer). 512 blocks = 2 blocks/CU.
// ---------------------------------------------------------------------------
__global__ __launch_bounds__(256) void proj_kernel(
    const __bf16* __restrict__ ao, const __bf16* __restrict__ Wo,
    const float* __restrict__ bo, float* __restrict__ out)
{
    __shared__ __align__(16) __bf16 ldsA[64 * 32];
    __shared__ __align__(16) __bf16 ldsB[128 * 32];

    const int tid  = threadIdx.x;
    const int lane = tid & 63, l16 = lane & 15, quad = lane >> 4;
    const int wiw  = tid >> 6;
    const int wm   = wiw & 1, wn = wiw >> 1;

    const int bm = blockIdx.x & 63;             // 64 m-tiles (M=4096, BM=64)
    const int bn = blockIdx.x >> 6;             // 8 n-tiles (N=1024, BN=128)
    const int m0 = bm * 64, n0 = bn * 128;

    const int srow = tid >> 2;                  // 0..63
    const int scol = (tid & 3) * 8;             // {0,8,16,24}

    floatx4 z = {0.f, 0.f, 0.f, 0.f};
    floatx4 acc[2][4];
    #pragma unroll
    for (int mt = 0; mt < 2; ++mt)
        #pragma unroll
        for (int nt = 0; nt < 4; ++nt) acc[mt][nt] = z;

    const __bf16* ga = ao + (size_t)m0 * Dmod;
    const __bf16* gb = Wo + (size_t)n0 * Dmod;

    for (int k0 = 0; k0 < Dmod; k0 += 32) {
        async_copy16(&ldsA[srow * 32 + scol],        ga + (size_t)srow * Dmod + k0 + scol);
        async_copy16(&ldsB[srow * 32 + scol],        gb + (size_t)srow * Dmod + k0 + scol);
        async_copy16(&ldsB[(64 + srow) * 32 + scol], gb + (size_t)(64 + srow) * Dmod + k0 + scol);
        __syncthreads();

        bf16x8 af[2], bfr[4];
        #pragma unroll
        for (int mt = 0; mt < 2; ++mt)
            af[mt] = *(const bf16x8*)&ldsA[(wm * 32 + mt * 16 + l16) * 32 + quad * 8];
        #pragma unroll
        for (int nt = 0; nt < 4; ++nt)
            bfr[nt] = *(const bf16x8*)&ldsB[(wn * 64 + nt * 16 + l16) * 32 + quad * 8];
        #pragma unroll
        for (int mt = 0; mt < 2; ++mt)
            #pragma unroll
            for (int nt = 0; nt < 4; ++nt)
                acc[mt][nt] = mfma16(af[mt], bfr[nt], acc[mt][nt]);
        __syncthreads();
    }

    const int nb = n0 + wn * 64;
    const int mw = m0 + wm * 32;
    #pragma unroll
    for (int nt = 0; nt < 4; ++nt) {
        float bias = bo[nb + nt * 16 + l16];
        #pragma unroll
        for (int mt = 0; mt < 2; ++mt)
            #pragma unroll
            for (int i = 0; i < 4; ++i) {
                int m = mw + mt * 16 + quad * 4 + i;
                out[(size_t)m * Dmod + nb + nt * 16 + l16] = acc[mt][nt][i] + bias;
            }
    }
}

// ---------------------------------------------------------------------------
extern "C" void kernel_launch(void* const* d_in, const int* in_sizes, int n_in,
                              void* d_out, int out_size, void* d_ws, size_t ws_size,
                              hipStream_t stream) {
    const float* x  = (const float*)d_in[0];
    const float* Wq = (const float*)d_in[1];
    const float* bq = (const float*)d_in[2];
    const float* Wo = (const float*)d_in[3];
    const float* bo = (const float*)d_in[4];
    float* out = (float*)d_out;

    __bf16* ws  = (__bf16*)d_ws;
    __bf16* xb  = ws;
    __bf16* wqb = ws + (size_t)XN;
    __bf16* wob = wqb + (size_t)WQN;
    __bf16* qb  = wob + (size_t)WON;
    const size_t SZ = (size_t)Bdim * Hn * Nseq * HDim;
    __bf16* kb  = qb + SZ;
    __bf16* vt  = kb + SZ;
    __bf16* ao  = vt + SZ;

    // 8.38M elems / 8 per thread / 256 = 4096 blocks
    convert_kernel<<<dim3(4096), dim3(256), 0, stream>>>(x, Wq, Wo, xb, wqb, wob);
    // 32 m-tiles x 24 n-tiles = 768 blocks (proven 128x128 tile, BK=32)
    qkv_kernel<<<dim3(768), dim3(256), 0, stream>>>(xb, wqb, bq, qb, kb, vt);
    // 32 bh x 16 q-blocks = 512 blocks, 128 q/block (32/wave), balanced remap
    attn_kernel<<<dim3(512), dim3(256), 0, stream>>>(qb, kb, vt, ao);
    // 64 m-tiles x 8 n-tiles = 512 blocks (2 blocks/CU)
    proj_kernel<<<dim3(512), dim3(256), 0, stream>>>(ao, wob, bo, out);
}

// Round 6
// 173.804 us; speedup vs baseline: 1.0509x; 1.0509x over previous
//
#include <hip/hip_runtime.h>
#include <hip/hip_bf16.h>

// Problem constants
#define Bdim 2
#define Nseq 2048
#define Dmod 1024
#define Hn   16
#define HDim 64

#define XN  (Bdim * Nseq * Dmod)        // 4,194,304
#define WQN (3 * Dmod * Dmod)           // 3,145,728
#define WON (Dmod * Dmod)               // 1,048,576

typedef __attribute__((ext_vector_type(8))) __bf16 bf16x8;
typedef __attribute__((ext_vector_type(4))) __bf16 bf16x4;
typedef __attribute__((ext_vector_type(4))) float  floatx4;

__device__ __forceinline__ floatx4 mfma16(bf16x8 a, bf16x8 b, floatx4 c) {
    return __builtin_amdgcn_mfma_f32_16x16x32_bf16(a, b, c, 0, 0, 0);
}

// native v_exp_f32 computes 2^x
__device__ __forceinline__ float exp2v(float x) {
    return __builtin_amdgcn_exp2f(x);
}

// async global->LDS, 16 B per lane (GEMMs only; attn uses swizzled ds_write).
__device__ __forceinline__ void async_copy16(__bf16* l, const __bf16* g) {
    __builtin_amdgcn_global_load_lds(
        (const __attribute__((address_space(1))) void*)g,
        (__attribute__((address_space(3))) void*)l,
        16, 0, 0);
}

// ---------------------------------------------------------------------------
// Kernel 0: fp32 -> bf16 conversion. 8 elems/thread: 2x float4 load (32 B)
// + 1x bf16x8 store (16 B/lane = coalescing sweet spot).
// ---------------------------------------------------------------------------
__global__ __launch_bounds__(256) void convert_kernel(
    const float* __restrict__ x, const float* __restrict__ wq,
    const float* __restrict__ wo,
    __bf16* __restrict__ xb, __bf16* __restrict__ wqb, __bf16* __restrict__ wob)
{
    int i = (blockIdx.x * 256 + threadIdx.x) * 8;
    const float* src;
    __bf16* dst;
    int off;
    if (i < XN)            { src = x;  dst = xb;  off = i; }
    else if (i < XN + WQN) { src = wq; dst = wqb; off = i - XN; }
    else                   { src = wo; dst = wob; off = i - XN - WQN; }
    float4 v0 = *(const float4*)(src + off);
    float4 v1 = *(const float4*)(src + off + 4);
    bf16x8 o;
    o[0] = (__bf16)v0.x; o[1] = (__bf16)v0.y; o[2] = (__bf16)v0.z; o[3] = (__bf16)v0.w;
    o[4] = (__bf16)v1.x; o[5] = (__bf16)v1.y; o[6] = (__bf16)v1.z; o[7] = (__bf16)v1.w;
    *(bf16x8*)(dst + off) = o;
}

// ---------------------------------------------------------------------------
// Kernel 1: QKV projection — 128x128 tile, BK=32, R6: STATIC double-buffer
// 2-phase pipeline. R4's dynamic-index dbuf failed because the compiler
// couldn't prove ds_read(buf[cur]) doesn't alias the in-flight
// global_load_lds writes to buf[nxt] and drained vmcnt(0) before the
// fragment reads. Four distinct __shared__ arrays + 2x-unrolled loop make
// the buffers statically disjoint: ds_reads issue freely, staged loads get
// the whole MFMA phase of flight, the only vmcnt(0) drain is at the barrier.
// Q third pre-scaled by C = hd^-0.5 * log2(e) (attention runs in log2 domain).
// ---------------------------------------------------------------------------
__global__ __launch_bounds__(256) void qkv_kernel(
    const __bf16* __restrict__ x, const __bf16* __restrict__ Wq,
    const float* __restrict__ bq,
    __bf16* __restrict__ qb, __bf16* __restrict__ kb, __bf16* __restrict__ vt)
{
    __shared__ __align__(16) __bf16 ldsA0[128 * 32];
    __shared__ __align__(16) __bf16 ldsA1[128 * 32];
    __shared__ __align__(16) __bf16 ldsB0[128 * 32];
    __shared__ __align__(16) __bf16 ldsB1[128 * 32];

    const int tid  = threadIdx.x;
    const int lane = tid & 63, l16 = lane & 15, quad = lane >> 4;
    const int wiw  = tid >> 6;
    const int wm   = wiw & 1, wn = wiw >> 1;

    const int bm = blockIdx.x & 31;             // 32 m-tiles (M=4096)
    const int bn = blockIdx.x >> 5;             // 24 n-tiles (N=3072)
    const int m0 = bm * 128, n0 = bn * 128;

    const int srow = tid >> 2;                  // staging row 0..63
    const int scol = (tid & 3) * 8;             // staging col {0,8,16,24}

    floatx4 z = {0.f, 0.f, 0.f, 0.f};
    floatx4 acc[4][4];
    #pragma unroll
    for (int mt = 0; mt < 4; ++mt)
        #pragma unroll
        for (int nt = 0; nt < 4; ++nt) acc[mt][nt] = z;

    const __bf16* ga = x  + (size_t)m0 * Dmod;
    const __bf16* gb = Wq + (size_t)n0 * Dmod;

    // staging helper (inlined; dA/dB resolve to distinct static arrays)
    auto STAGE = [&](__bf16* dA, __bf16* dB, int kk) {
        async_copy16(&dA[srow * 32 + scol],        ga + (size_t)srow * Dmod + kk + scol);
        async_copy16(&dA[(64 + srow) * 32 + scol], ga + (size_t)(64 + srow) * Dmod + kk + scol);
        async_copy16(&dB[srow * 32 + scol],        gb + (size_t)srow * Dmod + kk + scol);
        async_copy16(&dB[(64 + srow) * 32 + scol], gb + (size_t)(64 + srow) * Dmod + kk + scol);
    };

    // prologue: K-step 0 into buf0
    STAGE(ldsA0, ldsB0, 0);
    __syncthreads();

    for (int k0 = 0; k0 < Dmod; k0 += 64) {
        // ---- even step: compute buf0, stage k0+32 into buf1 ----
        {
            bf16x8 af[4], bfr[4];
            #pragma unroll
            for (int mt = 0; mt < 4; ++mt)
                af[mt] = *(const bf16x8*)&ldsA0[(wm * 64 + mt * 16 + l16) * 32 + quad * 8];
            #pragma unroll
            for (int nt = 0; nt < 4; ++nt)
                bfr[nt] = *(const bf16x8*)&ldsB0[(wn * 64 + nt * 16 + l16) * 32 + quad * 8];
            STAGE(ldsA1, ldsB1, k0 + 32);       // flies during MFMA below
            #pragma unroll
            for (int mt = 0; mt < 4; ++mt)
                #pragma unroll
                for (int nt = 0; nt < 4; ++nt)
                    acc[mt][nt] = mfma16(af[mt], bfr[nt], acc[mt][nt]);
            __syncthreads();                    // publishes buf1, retires buf0
        }
        // ---- odd step: compute buf1, stage k0+64 into buf0 ----
        {
            bf16x8 af[4], bfr[4];
            #pragma unroll
            for (int mt = 0; mt < 4; ++mt)
                af[mt] = *(const bf16x8*)&ldsA1[(wm * 64 + mt * 16 + l16) * 32 + quad * 8];
            #pragma unroll
            for (int nt = 0; nt < 4; ++nt)
                bfr[nt] = *(const bf16x8*)&ldsB1[(wn * 64 + nt * 16 + l16) * 32 + quad * 8];
            if (k0 + 64 < Dmod)
                STAGE(ldsA0, ldsB0, k0 + 64);
            #pragma unroll
            for (int mt = 0; mt < 4; ++mt)
                #pragma unroll
                for (int nt = 0; nt < 4; ++nt)
                    acc[mt][nt] = mfma16(af[mt], bfr[nt], acc[mt][nt]);
            __syncthreads();
        }
    }

    const int nb    = n0 + wn * 64;
    const int which = nb >> 10;
    const int h     = (nb & 1023) >> 6;
    const int mw    = m0 + wm * 64;
    const int bi    = mw >> 11;
    const int pos0  = mw & (Nseq - 1);

    const float qscale = 0.18033688f;           // 0.125 * log2(e)

    #pragma unroll
    for (int nt = 0; nt < 4; ++nt) {
        float bias = bq[nb + nt * 16 + l16];
        int hd = nt * 16 + l16;
        #pragma unroll
        for (int mt = 0; mt < 4; ++mt)
            #pragma unroll
            for (int i = 0; i < 4; ++i) {
                int pos = pos0 + mt * 16 + quad * 4 + i;
                float r = acc[mt][nt][i] + bias;
                if (which == 0)
                    qb[((bi * Hn + h) * Nseq + pos) * HDim + hd] = (__bf16)(r * qscale);
                else if (which == 1)
                    kb[((bi * Hn + h) * Nseq + pos) * HDim + hd] = (__bf16)r;
                else
                    vt[((bi * Hn + h) * HDim + hd) * Nseq + pos] = (__bf16)r;
            }
    }
}

// ---------------------------------------------------------------------------
// Kernel 2: causal flash attention, block-cooperative — PROVEN R1 version
// restored verbatim (1024 blocks, 16 q/wave, 4 blocks/CU). R5's 32 q/wave
// halved the grid to 2 blocks/CU and regressed (48.9us, occupancy 12%):
// wave-parallelism is the latency-hiding resource here, not work-efficiency.
// Keeps: LDS-staged K/V with register prefetch, balanced per-CU qblk remap,
// scale folded into Q, ones-MFMA row-sum, defer-max THR=8, setprio.
// ---------------------------------------------------------------------------
__global__ __launch_bounds__(256, 4) void attn_kernel(
    const __bf16* __restrict__ qbuf, const __bf16* __restrict__ kbuf,
    const __bf16* __restrict__ vtbuf, __bf16* __restrict__ aout)
{
    __shared__ __align__(16) __bf16 ldsK[64 * 64];   // [key][d], swizzled
    __shared__ __align__(16) __bf16 ldsV[64 * 64];   // [d][key], swizzled
    __shared__ __align__(16) __bf16 ldsP[4][16 * 72];

    const int tid  = threadIdx.x;
    const int wiw  = tid >> 6;
    const int lane = tid & 63, l16 = lane & 15, quad = lane >> 4;
    const int b    = blockIdx.x;
    const int bh   = b & 31;                    // head: all 32 q-blocks of a
                                                // head share one XCD (b%8)
    // Balanced qblk remap: CU hosts blocks {i, i+256, i+512, i+768} ->
    // g-groups {k, k+8, k+16, k+24} -> qblk {31-k, k, 23-k, 8+k},
    // per-CU work = (32-k)+(k+1)+(24-k)+(9+k) = 66 tiles for every k.
    const int g  = b >> 5;
    const int gk = g & 7, r4 = g >> 3;
    int qblk;
    if      (r4 == 0) qblk = 31 - gk;
    else if (r4 == 1) qblk = gk;
    else if (r4 == 2) qblk = 23 - gk;
    else              qblk = 8 + gk;

    const int q0 = qblk * 64 + wiw * 16;        // this wave's 16 queries

    const __bf16* qs = qbuf  + bh * Nseq * HDim;
    const __bf16* ks = kbuf  + bh * Nseq * HDim;
    const __bf16* vs = vtbuf + bh * HDim * Nseq;

    // staging coords: thread handles rows sr, sr+32; 16B block sb
    const int sr  = tid >> 3;                   // 0..31
    const int sb  = tid & 7;                    // 0..7
    const int swr = (sb ^ (sr & 7)) * 8;        // swizzled block offset (elems)
    const int wk0 = sr * 64 + swr;              // (sr+32)&7 == sr&7
    const int wk1 = (sr + 32) * 64 + swr;

    // Q as B-operand: lane l16 = q row, k = d = quad*8+j  (pre-scaled by C)
    bf16x8 qf0 = *(const bf16x8*)(qs + (q0 + l16) * HDim + quad * 8);
    bf16x8 qf1 = *(const bf16x8*)(qs + (q0 + l16) * HDim + 32 + quad * 8);

    floatx4 z = {0.f, 0.f, 0.f, 0.f};
    floatx4 o[4];
    #pragma unroll
    for (int s = 0; s < 4; ++s) o[s] = z;
    floatx4 lacc = z;                           // row-sum accumulator (ones-MFMA)
    float m_i = -1e30f;                         // per-lane: q = q0 + l16

    bf16x8 ones;
    #pragma unroll
    for (int j = 0; j < 8; ++j) ones[j] = (__bf16)1.0f;

    const int   nkt = qblk + 1;                 // 64-key tiles (uniform in block)
    __bf16* myp = ldsP[wiw];
    const int swz = l16 & 7;                    // read-side swizzle (row&7)

    // prefetch tile 0 into registers
    float4 rk0 = *(const float4*)(ks + (size_t)sr * HDim + sb * 8);
    float4 rk1 = *(const float4*)(ks + (size_t)(sr + 32) * HDim + sb * 8);
    float4 rv0 = *(const float4*)(vs + (size_t)sr * Nseq + sb * 8);
    float4 rv1 = *(const float4*)(vs + (size_t)(sr + 32) * Nseq + sb * 8);

    for (int kt = 0; kt < nkt; ++kt) {
        // issue next tile's global loads first (in flight during compute)
        float4 nk0 = {}, nk1 = {}, nv0 = {}, nv1 = {};
        if (kt + 1 < nkt) {
            const int k0n = (kt + 1) * 64;
            nk0 = *(const float4*)(ks + (size_t)(k0n + sr) * HDim + sb * 8);
            nk1 = *(const float4*)(ks + (size_t)(k0n + sr + 32) * HDim + sb * 8);
            nv0 = *(const float4*)(vs + (size_t)sr * Nseq + k0n + sb * 8);
            nv1 = *(const float4*)(vs + (size_t)(sr + 32) * Nseq + k0n + sb * 8);
        }

        // write current tile to LDS (swizzled)
        *(float4*)&ldsK[wk0] = rk0;
        *(float4*)&ldsK[wk1] = rk1;
        *(float4*)&ldsV[wk0] = rv0;
        *(float4*)&ldsV[wk1] = rv1;
        __syncthreads();

        const bool last = (kt == nkt - 1);

        // S^T: 4 subtiles of 16 keys. A=K (m=key), B=Q (n=q).
        floatx4 st[4];
        __builtin_amdgcn_s_setprio(1);
        #pragma unroll
        for (int t = 0; t < 4; ++t) {
            const __bf16* kr = &ldsK[(t * 16 + l16) * 64];
            bf16x8 kf0 = *(const bf16x8*)(kr + ((quad ^ swz) * 8));
            bf16x8 kf1 = *(const bf16x8*)(kr + (((quad + 4) ^ swz) * 8));
            st[t] = mfma16(kf0, qf0, z);
            st[t] = mfma16(kf1, qf1, st[t]);
        }
        __builtin_amdgcn_s_setprio(0);

        // scores (log2 domain, scale pre-folded into Q);
        // lane holds keys {16t+quad*4+i} for q=q0+l16
        float a[16];
        #pragma unroll
        for (int t = 0; t < 4; ++t)
            #pragma unroll
            for (int i = 0; i < 4; ++i) {
                float v = st[t][i];
                if (last) {
                    int kidx = t * 16 + quad * 4 + i;      // key - k0
                    v = (kidx <= wiw * 16 + l16) ? v : -1e30f;
                }
                a[t * 4 + i] = v;
            }

        // row max: max3-shaped tree + 2 cross-quad shuffles
        float m0 = fmaxf(fmaxf(a[0],  a[1]),  a[2]);
        float m1 = fmaxf(fmaxf(a[3],  a[4]),  a[5]);
        float m2 = fmaxf(fmaxf(a[6],  a[7]),  a[8]);
        float m3 = fmaxf(fmaxf(a[9],  a[10]), a[11]);
        float m4 = fmaxf(fmaxf(a[12], a[13]), a[14]);
        float mx = fmaxf(fmaxf(fmaxf(m0, m1), m2),
                         fmaxf(fmaxf(m3, m4), a[15]));
        mx = fmaxf(mx, __shfl_xor(mx, 16));
        mx = fmaxf(mx, __shfl_xor(mx, 32));

        // defer-max: only rescale when some row's max grew by >8 (log2 units);
        // otherwise keep m_i, P bounded by 2^8 = 256 (fine in bf16/f32).
        if (__any(mx > m_i + 8.0f)) {
            float mn    = fmaxf(m_i, mx);
            float alpha = exp2v(m_i - mn);
            #pragma unroll
            for (int s = 0; s < 4; ++s)
                #pragma unroll
                for (int i = 0; i < 4; ++i) o[s][i] *= alpha;
            #pragma unroll
            for (int i = 0; i < 4; ++i) lacc[i] *= alpha;
            m_i = mn;
        }

        float p[16];
        #pragma unroll
        for (int j = 0; j < 16; ++j) p[j] = exp2v(a[j] - m_i);

        // P: C-layout -> LDS -> B-layout (per-wave region, stride 72)
        #pragma unroll
        for (int t = 0; t < 4; ++t) {
            bf16x4 pk;
            pk.x = (__bf16)p[t * 4 + 0]; pk.y = (__bf16)p[t * 4 + 1];
            pk.z = (__bf16)p[t * 4 + 2]; pk.w = (__bf16)p[t * 4 + 3];
            *(bf16x4*)(myp + l16 * 72 + t * 16 + quad * 4) = pk;
        }
        asm volatile("s_waitcnt lgkmcnt(0)" ::: "memory");
        bf16x8 pf0 = *(const bf16x8*)(myp + l16 * 72 + quad * 8);
        bf16x8 pf1 = *(const bf16x8*)(myp + l16 * 72 + 32 + quad * 8);

        __builtin_amdgcn_s_setprio(1);
        // row-sum via ones-MFMA: lacc rows all = sum_k P[q][k] (bf16 P —
        // consistent with the P used for O, so O/l is a true weighted mean)
        lacc = mfma16(ones, pf0, lacc);
        lacc = mfma16(ones, pf1, lacc);

        // O^T += V^T P^T : A=V^T (m=d, k=key) from LDS (swizzled)
        #pragma unroll
        for (int s = 0; s < 4; ++s) {
            const __bf16* vr = &ldsV[(s * 16 + l16) * 64];
            bf16x8 vf0 = *(const bf16x8*)(vr + ((quad ^ swz) * 8));
            bf16x8 vf1 = *(const bf16x8*)(vr + (((quad + 4) ^ swz) * 8));
            o[s] = mfma16(vf0, pf0, o[s]);
            o[s] = mfma16(vf1, pf1, o[s]);
        }
        __builtin_amdgcn_s_setprio(0);
        __syncthreads();                        // all waves done with K/V tile

        rk0 = nk0; rk1 = nk1; rv0 = nv0; rv1 = nv1;
    }

    // Epilogue: O^T tile s: row = d = s*16+quad*4+i, col = q = q0+l16
    const float inv = 1.0f / lacc[0];           // all lacc rows identical
    const int bi = bh >> 4, h = bh & 15;
    #pragma unroll
    for (int s = 0; s < 4; ++s) {
        bf16x4 ov;
        ov.x = (__bf16)(o[s][0] * inv); ov.y = (__bf16)(o[s][1] * inv);
        ov.z = (__bf16)(o[s][2] * inv); ov.w = (__bf16)(o[s][3] * inv);
        *(bf16x4*)(aout + ((size_t)(bi * Nseq + q0 + l16)) * Dmod
                   + h * 64 + s * 16 + quad * 4) = ov;
    }
}

// ---------------------------------------------------------------------------
// Kernel 3: output projection — PROVEN R1 version (BM=64 x BN=128, BK=32,
// single-buffer). Grid 64 m-tiles x 8 n-tiles = 512 blocks = 2 blocks/CU.
// ---------------------------------------------------------------------------
__global__ __launch_bounds__(256) void proj_kernel(
    const __bf16* __restrict__ ao, const __bf16* __restrict__ Wo,
    const float* __restrict__ bo, float* __restrict__ out)
{
    __shared__ __align__(16) __bf16 ldsA[64 * 32];
    __shared__ __align__(16) __bf16 ldsB[128 * 32];

    const int tid  = threadIdx.x;
    const int lane = tid & 63, l16 = lane & 15, quad = lane >> 4;
    const int wiw  = tid >> 6;
    const int wm   = wiw & 1, wn = wiw >> 1;

    const int bm = blockIdx.x & 63;             // 64 m-tiles (M=4096, BM=64)
    const int bn = blockIdx.x >> 6;             // 8 n-tiles (N=1024, BN=128)
    const int m0 = bm * 64, n0 = bn * 128;

    const int srow = tid >> 2;                  // 0..63
    const int scol = (tid & 3) * 8;             // {0,8,16,24}

    floatx4 z = {0.f, 0.f, 0.f, 0.f};
    floatx4 acc[2][4];
    #pragma unroll
    for (int mt = 0; mt < 2; ++mt)
        #pragma unroll
        for (int nt = 0; nt < 4; ++nt) acc[mt][nt] = z;

    const __bf16* ga = ao + (size_t)m0 * Dmod;
    const __bf16* gb = Wo + (size_t)n0 * Dmod;

    for (int k0 = 0; k0 < Dmod; k0 += 32) {
        async_copy16(&ldsA[srow * 32 + scol],        ga + (size_t)srow * Dmod + k0 + scol);
        async_copy16(&ldsB[srow * 32 + scol],        gb + (size_t)srow * Dmod + k0 + scol);
        async_copy16(&ldsB[(64 + srow) * 32 + scol], gb + (size_t)(64 + srow) * Dmod + k0 + scol);
        __syncthreads();

        bf16x8 af[2], bfr[4];
        #pragma unroll
        for (int mt = 0; mt < 2; ++mt)
            af[mt] = *(const bf16x8*)&ldsA[(wm * 32 + mt * 16 + l16) * 32 + quad * 8];
        #pragma unroll
        for (int nt = 0; nt < 4; ++nt)
            bfr[nt] = *(const bf16x8*)&ldsB[(wn * 64 + nt * 16 + l16) * 32 + quad * 8];
        #pragma unroll
        for (int mt = 0; mt < 2; ++mt)
            #pragma unroll
            for (int nt = 0; nt < 4; ++nt)
                acc[mt][nt] = mfma16(af[mt], bfr[nt], acc[mt][nt]);
        __syncthreads();
    }

    const int nb = n0 + wn * 64;
    const int mw = m0 + wm * 32;
    #pragma unroll
    for (int nt = 0; nt < 4; ++nt) {
        float bias = bo[nb + nt * 16 + l16];
        #pragma unroll
        for (int mt = 0; mt < 2; ++mt)
            #pragma unroll
            for (int i = 0; i < 4; ++i) {
                int m = mw + mt * 16 + quad * 4 + i;
                out[(size_t)m * Dmod + nb + nt * 16 + l16] = acc[mt][nt][i] + bias;
            }
    }
}

// ---------------------------------------------------------------------------
extern "C" void kernel_launch(void* const* d_in, const int* in_sizes, int n_in,
                              void* d_out, int out_size, void* d_ws, size_t ws_size,
                              hipStream_t stream) {
    const float* x  = (const float*)d_in[0];
    const float* Wq = (const float*)d_in[1];
    const float* bq = (const float*)d_in[2];
    const float* Wo = (const float*)d_in[3];
    const float* bo = (const float*)d_in[4];
    float* out = (float*)d_out;

    __bf16* ws  = (__bf16*)d_ws;
    __bf16* xb  = ws;
    __bf16* wqb = ws + (size_t)XN;
    __bf16* wob = wqb + (size_t)WQN;
    __bf16* qb  = wob + (size_t)WON;
    const size_t SZ = (size_t)Bdim * Hn * Nseq * HDim;
    __bf16* kb  = qb + SZ;
    __bf16* vt  = kb + SZ;
    __bf16* ao  = vt + SZ;

    // 8.38M elems / 8 per thread / 256 = 4096 blocks
    convert_kernel<<<dim3(4096), dim3(256), 0, stream>>>(x, Wq, Wo, xb, wqb, wob);
    // 32 m-tiles x 24 n-tiles = 768 blocks (128x128, BK=32, static dbuf)
    qkv_kernel<<<dim3(768), dim3(256), 0, stream>>>(xb, wqb, bq, qb, kb, vt);
    // 32 bh x 32 q-blocks = 1024 blocks, 4 waves each, balanced remap
    attn_kernel<<<dim3(1024), dim3(256), 0, stream>>>(qb, kb, vt, ao);
    // 64 m-tiles x 8 n-tiles = 512 blocks (2 blocks/CU)
    proj_kernel<<<dim3(512), dim3(256), 0, stream>>>(ao, wob, bo, out);
}